// Round 5
// baseline (262.272 us; speedup 1.0000x reference)
//
#include <hip/hip_runtime.h>
#include <hip/hip_bf16.h>

#define EPS 1e-3f

typedef __attribute__((ext_vector_type(8))) short short8;
typedef __attribute__((ext_vector_type(4))) float v4f;

__device__ __forceinline__ unsigned short f2bf(float f) {
    unsigned int u = __float_as_uint(f);
    unsigned int r = (u + 0x7fffu + ((u >> 16) & 1u)) >> 16;
    return (unsigned short)r;
}

// ---------------------------------------------------------------------------
// Prep: fold biases + BN into per-channel affine; transpose pw_kernel into
// bf16 MFMA B-fragment layout.
// ---------------------------------------------------------------------------
__global__ __launch_bounds__(256) void prep_kernel(
    const float* __restrict__ dwb,
    const float* __restrict__ g1, const float* __restrict__ b1,
    const float* __restrict__ m1, const float* __restrict__ v1,
    const float* __restrict__ pw, const float* __restrict__ pwb,
    const float* __restrict__ g2, const float* __restrict__ b2,
    const float* __restrict__ m2, const float* __restrict__ v2,
    float* __restrict__ scale1, float* __restrict__ shift1,
    float* __restrict__ s2, float* __restrict__ t2,
    unsigned short* __restrict__ Wt)
{
    int tid = threadIdx.x;
    if (blockIdx.x == 0) {
        if (tid < 64) {
            float inv = g1[tid] * rsqrtf(v1[tid] + EPS);
            scale1[tid] = inv;
            shift1[tid] = dwb[tid] * inv + b1[tid] - m1[tid] * inv;
        }
        if (tid < 128) {
            float inv = g2[tid] * rsqrtf(v2[tid] + EPS);
            s2[tid] = inv;
            t2[tid] = pwb[tid] * inv + b2[tid] - m2[tid] * inv;
        }
    }
    int idx = blockIdx.x * 256 + tid;      // 0..8191
    int j     = idx & 7;
    int lane  = (idx >> 3) & 63;
    int kstep = (idx >> 9) & 1;
    int ntile = idx >> 10;                 // 0..7
    int k = kstep * 32 + (lane >> 4) * 8 + j;
    int f = ntile * 16 + (lane & 15);
    Wt[idx] = f2bf(pw[k * 128 + f]);
}

// ---------------------------------------------------------------------------
// Fused: dw 3x3x3 conv + BN1 + ReLU -> bf16 LDS tile -> MFMA pointwise GEMM
// + BN2 + ReLU -> out.
// Block: 256 thr, tile = 4(h) x 16(w) x 2(d) = 128 GEMM rows.
// Branchless conv: invalid d/h taps redirect the weight pointer to a zeroed
// LDS page (wZ) -> no branches between load batches -> software pipeline:
//   load S0,S1; FMA S0; load S2; FMA S1; load S3; FMA S2; FMA S3
// Slab si (zd = d0-1+si) feeds output o=0 (dd=si) and o=1 (dd=si-1).
// ---------------------------------------------------------------------------
__global__ __launch_bounds__(256) void fused_kernel(
    const float* __restrict__ x,
    const float* __restrict__ wgt,          // (3,3,3,1,64)
    const float* __restrict__ scale1,
    const float* __restrict__ shift1,
    const unsigned short* __restrict__ Wt,  // bf16 B-fragments (16 KB)
    const float* __restrict__ s2,
    const float* __restrict__ t2,
    float* __restrict__ out)
{
    __shared__ float wS[27 * 64];
    __shared__ float wZ[192];               // zero page for invalid taps
    __shared__ float sS[64];
    __shared__ float tS[64];
    __shared__ unsigned short yS[128 * 72]; // 128 rows x 64 ch, +8 pad

    int tid = threadIdx.x;
    for (int i = tid; i < 27 * 64; i += 256) wS[i] = wgt[i];
    if (tid < 192) wZ[tid] = 0.f;
    if (tid < 64) { sS[tid] = scale1[tid]; tS[tid] = shift1[tid]; }
    __syncthreads();

    // XCD-aware decode: xcd = n&7 owns 6 consecutive bd2 values
    int n   = blockIdx.x;
    int xcd = n & 7;
    int j   = n >> 3;              // 0..215
    int bd2 = xcd * 6 + (j % 6);   // 0..47
    int s   = j / 6;               // 0..35
    int w0  = (s % 3) * 16;
    int h0  = (s / 3) * 4;
    int b   = bd2 / 24;
    int d0  = (bd2 % 24) * 2;

    int tx = tid & 15;            // channel group
    int ty = tid >> 4;            // 0..15
    int c0 = tx * 4;
    int wq = ty & 3;
    int rh = ty >> 2;             // == wave id -> h wave-uniform
    int w0t = w0 + wq * 4;
    int h   = h0 + rh;

    float4 acc0[4], acc1[4];
    #pragma unroll
    for (int r = 0; r < 4; ++r) {
        acc0[r] = make_float4(0.f, 0.f, 0.f, 0.f);
        acc1[r] = make_float4(0.f, 0.f, 0.f, 0.f);
    }

    float mwL = (w0t >= 1)  ? 1.f : 0.f;
    float mwR = (w0t <= 43) ? 1.f : 0.f;
    int wcl[6];
    #pragma unroll
    for (int p = 0; p < 6; ++p)
        wcl[p] = min(max(w0t - 1 + p, 0), 47) * 64;

    bool hok[3];
    int  hcl[3];
    #pragma unroll
    for (int hh = 0; hh < 3; ++hh) {
        int zh = h + hh - 1;
        hok[hh] = (zh >= 0 && zh < 48);
        hcl[hh] = min(max(zh, 0), 47) * 48 * 64;
    }

    const float* xb = x + ((long)b * 48) * 147456 + c0;

    // slab loader: 18 unconditional clamped loads
    auto loadSlab = [&](float4* Xb, int si) {
        int zdc = min(max(d0 - 1 + si, 0), 47);
        const float* dp = xb + (long)zdc * 147456;
        #pragma unroll
        for (int hh = 0; hh < 3; ++hh) {
            const float* rowp = dp + hcl[hh];
            #pragma unroll
            for (int p = 0; p < 6; ++p)
                Xb[hh * 6 + p] = *(const float4*)(rowp + wcl[p]);
        }
    };

    // FMA one (slab, output) pair; weight row redirected to wZ when invalid
    auto fmaOne = [&](const float4* Xb, int dd, float4* accp, bool dok) {
        #pragma unroll
        for (int hh = 0; hh < 3; ++hh) {
            const float* wp = (dok && hok[hh]) ? &wS[(dd * 3 + hh) * 192 + c0]
                                               : &wZ[c0];
            #pragma unroll
            for (int ww = 0; ww < 3; ++ww) {
                const float4 wv = *(const float4*)(wp + ww * 64);
                #pragma unroll
                for (int r = 0; r < 4; ++r) {
                    accp[r].x += Xb[hh * 6 + r + ww].x * wv.x;
                    accp[r].y += Xb[hh * 6 + r + ww].y * wv.y;
                    accp[r].z += Xb[hh * 6 + r + ww].z * wv.z;
                    accp[r].w += Xb[hh * 6 + r + ww].w * wv.w;
                }
            }
        }
    };

    auto maskEdges = [&](float4* Xb) {
        #pragma unroll
        for (int hh = 0; hh < 3; ++hh) {
            Xb[hh * 6 + 0].x *= mwL; Xb[hh * 6 + 0].y *= mwL;
            Xb[hh * 6 + 0].z *= mwL; Xb[hh * 6 + 0].w *= mwL;
            Xb[hh * 6 + 5].x *= mwR; Xb[hh * 6 + 5].y *= mwR;
            Xb[hh * 6 + 5].z *= mwR; Xb[hh * 6 + 5].w *= mwR;
        }
    };

    bool dv0 = (d0 - 1 >= 0);      // slab 0 validity (zd = d0-1)
    bool dv3 = (d0 + 2 < 48);      // slab 3 validity (zd = d0+2)

    float4 X[18], Y[18];
    loadSlab(X, 0);
    loadSlab(Y, 1);

    // slab 0: o=0 dd=0
    maskEdges(X);
    fmaOne(X, 0, acc0, dv0);
    loadSlab(X, 2);

    // slab 1: o=0 dd=1 ; o=1 dd=0 (always valid: zd = d0)
    maskEdges(Y);
    fmaOne(Y, 1, acc0, true);
    fmaOne(Y, 0, acc1, true);
    loadSlab(Y, 3);

    // slab 2: o=0 dd=2 ; o=1 dd=1 (zd = d0+1 always valid)
    maskEdges(X);
    fmaOne(X, 2, acc0, true);
    fmaOne(X, 1, acc1, true);

    // slab 3: o=1 dd=2
    maskEdges(Y);
    fmaOne(Y, 2, acc1, dv3);

    // BN1 + ReLU + bf16 -> LDS rows o*64 + ty*4+r (stride 72 shorts)
    {
        float4 s1 = *(const float4*)(&sS[c0]);
        float4 t1 = *(const float4*)(&tS[c0]);
        #pragma unroll
        for (int r = 0; r < 4; ++r) {
            ushort4 o0, o1;
            o0.x = f2bf(fmaxf(acc0[r].x * s1.x + t1.x, 0.f));
            o0.y = f2bf(fmaxf(acc0[r].y * s1.y + t1.y, 0.f));
            o0.z = f2bf(fmaxf(acc0[r].z * s1.z + t1.z, 0.f));
            o0.w = f2bf(fmaxf(acc0[r].w * s1.w + t1.w, 0.f));
            o1.x = f2bf(fmaxf(acc1[r].x * s1.x + t1.x, 0.f));
            o1.y = f2bf(fmaxf(acc1[r].y * s1.y + t1.y, 0.f));
            o1.z = f2bf(fmaxf(acc1[r].z * s1.z + t1.z, 0.f));
            o1.w = f2bf(fmaxf(acc1[r].w * s1.w + t1.w, 0.f));
            *(ushort4*)(&yS[(ty * 4 + r) * 72 + c0]) = o0;
            *(ushort4*)(&yS[(64 + ty * 4 + r) * 72 + c0]) = o1;
        }
    }
    __syncthreads();

    // GEMM: 4 waves, each does o=0,1: 16 rows x 128 cols, K=64
    int wv   = tid >> 6;
    int lane = tid & 63;
    int lrow = lane & 15;
    int quad = lane >> 4;

    short8 bf0[8], bf1[8];
    #pragma unroll
    for (int nn = 0; nn < 8; ++nn) {
        bf0[nn] = *(const short8*)(Wt + ((nn * 2 + 0) * 64 + lane) * 8);
        bf1[nn] = *(const short8*)(Wt + ((nn * 2 + 1) * 64 + lane) * 8);
    }
    float sf[8], tf[8];
    #pragma unroll
    for (int nn = 0; nn < 8; ++nn) {
        sf[nn] = s2[nn * 16 + lrow];
        tf[nn] = t2[nn * 16 + lrow];
    }

    #pragma unroll
    for (int o = 0; o < 2; ++o) {
        const short8 a0 = *(const short8*)(&yS[(o * 64 + wv * 16 + lrow) * 72 + quad * 8]);
        const short8 a1 = *(const short8*)(&yS[(o * 64 + wv * 16 + lrow) * 72 + 32 + quad * 8]);

        v4f g[8];
        #pragma unroll
        for (int nn = 0; nn < 8; ++nn) g[nn] = (v4f){0.f, 0.f, 0.f, 0.f};
        #pragma unroll
        for (int nn = 0; nn < 8; ++nn) {
            g[nn] = __builtin_amdgcn_mfma_f32_16x16x32_bf16(a0, bf0[nn], g[nn], 0, 0, 0);
            g[nn] = __builtin_amdgcn_mfma_f32_16x16x32_bf16(a1, bf1[nn], g[nn], 0, 0, 0);
        }

        long base_out = ((((long)b * 48 + d0 + o) * 48 + (h0 + wv)) * 48 + w0) * 128;
        #pragma unroll
        for (int nn = 0; nn < 8; ++nn) {
            int f = nn * 16 + lrow;
            #pragma unroll
            for (int r = 0; r < 4; ++r) {
                float v = fmaxf(g[nn][r] * sf[nn] + tf[nn], 0.f);
                out[base_out + (quad * 4 + r) * 128 + f] = v;
            }
        }
    }
}

// ---------------------------------------------------------------------------
extern "C" void kernel_launch(void* const* d_in, const int* in_sizes, int n_in,
                              void* d_out, int out_size, void* d_ws, size_t ws_size,
                              hipStream_t stream)
{
    const float* x   = (const float*)d_in[0];
    const float* dwk = (const float*)d_in[1];
    const float* dwb = (const float*)d_in[2];
    const float* g1  = (const float*)d_in[3];
    const float* b1  = (const float*)d_in[4];
    const float* m1  = (const float*)d_in[5];
    const float* v1  = (const float*)d_in[6];
    const float* pw  = (const float*)d_in[7];
    const float* pwb = (const float*)d_in[8];
    const float* g2  = (const float*)d_in[9];
    const float* b2  = (const float*)d_in[10];
    const float* m2  = (const float*)d_in[11];
    const float* v2  = (const float*)d_in[12];

    float* outp = (float*)d_out;

    float* scale1 = (float*)d_ws;
    float* shift1 = scale1 + 64;
    float* s2     = scale1 + 128;
    float* t2     = scale1 + 256;
    unsigned short* Wt = (unsigned short*)((char*)d_ws + 2048);

    hipLaunchKernelGGL(prep_kernel, dim3(32), dim3(256), 0, stream,
                       dwb, g1, b1, m1, v1, pw, pwb, g2, b2, m2, v2,
                       scale1, shift1, s2, t2, Wt);

    hipLaunchKernelGGL(fused_kernel, dim3(1728), dim3(256), 0, stream,
                       x, dwk, scale1, shift1, Wt, s2, t2, outp);
}